// Round 12
// baseline (210.542 us; speedup 1.0000x reference)
//
#include <hip/hip_runtime.h>
#include <math.h>

// HyperbolicMultiHeadAttention — round 25 (GEMMs reverted to r23; attn de-grouped):
//  * gemm_qkv / gemm_out: r23 serial-staging versions (r24's 48KB dbuf cut
//    qkv occupancy 6->3 blocks/CU; overlap gain < TLP loss, net +2.3us).
//  * attn_mfma: NO in-block split-K. 256-thread blocks (4 waves), 64 q rows x
//    all 1024 t (16 chunks). r23's rotated schedule kept: ds_read -> QK ->
//    barrier -> stage(ch+2)+norms(ch+1) -> scores -> PV. LDS 32KB ->
//    4 independent blocks/CU (vs 2 lockstep 8-wave); barriers sync 4 waves;
//    split-K LDS exchange + tail barriers gone (in-register epilogue).
//    Grid (bh=32, qt=16) keeps XCD pinning.
// B=2, S=1024, D=1024, H=16, dh=64.

#define EPS_ 1e-5f

constexpr int Ss = 1024, Dd = 1024, Hh = 16, DHh = 64;

typedef __attribute__((ext_vector_type(8))) short bf16x8;
typedef __attribute__((ext_vector_type(4))) short s16x4;
typedef __attribute__((ext_vector_type(4))) float f32x4;

__device__ __forceinline__ float softplusf_(float x) {
    return (x > 20.f) ? x : log1pf(expf(x));
}
__device__ __forceinline__ short f2bf(float f) {
    union { float f; unsigned u; } v; v.f = f;
    unsigned r = v.u + 0x7FFFu + ((v.u >> 16) & 1u);   // RNE
    return (short)(r >> 16);
}
__device__ __forceinline__ unsigned pks(short a, short b) {
    return (unsigned)(unsigned short)a | ((unsigned)(unsigned short)b << 16);
}

#if __has_builtin(__builtin_amdgcn_cvt_pk_bf16_f32)
typedef __attribute__((ext_vector_type(2))) __bf16 bfp2;
__device__ __forceinline__ unsigned cvtpk(float a, float b) {
    union { bfp2 v; unsigned u; } x;
    x.v = __builtin_amdgcn_cvt_pk_bf16_f32(a, b);
    return x.u;
}
#else
__device__ __forceinline__ unsigned cvtpk(float a, float b) { return pks(f2bf(a), f2bf(b)); }
#endif

#if __has_builtin(__builtin_amdgcn_sqrtf)
#define FSQRT __builtin_amdgcn_sqrtf
#else
#define FSQRT sqrtf
#endif
#if __has_builtin(__builtin_amdgcn_logf)
#define FLOG2 __builtin_amdgcn_logf
#else
#define FLOG2 __log2f
#endif
#if __has_builtin(__builtin_amdgcn_exp2f)
#define FEXP2 __builtin_amdgcn_exp2f
#else
#define FEXP2 exp2f
#endif

// async global->LDS, 16B per lane, linear LDS dest (wave base + lane*16)
__device__ __forceinline__ void gload_lds16(const short* gp, short* lp) {
    __builtin_amdgcn_global_load_lds(
        (__attribute__((address_space(1))) void*)(void*)(const_cast<short*>(gp)),
        (__attribute__((address_space(3))) void*)(void*)(lp), 16, 0, 0);
}

// ---------------- fp32 -> bf16 conversion (x, Wq, Wk, Wv, Wo) ----------------
__global__ __launch_bounds__(256) void split_all(
    const float* __restrict__ x,  const float* __restrict__ Wq,
    const float* __restrict__ Wk, const float* __restrict__ Wv,
    const float* __restrict__ Wo,
    short* __restrict__ xh,  short* __restrict__ wqh,
    short* __restrict__ wkh, short* __restrict__ wvh, short* __restrict__ woh)
{
    int g = blockIdx.x * 256 + threadIdx.x;
    const float* src; short* dst; int base;
    if (g < 524288)       { src = x;  dst = xh;  base = g; }
    else if (g < 786432)  { src = Wq; dst = wqh; base = g - 524288; }
    else if (g < 1048576) { src = Wk; dst = wkh; base = g - 786432; }
    else if (g < 1310720) { src = Wv; dst = wvh; base = g - 1048576; }
    else                  { src = Wo; dst = woh; base = g - 1310720; }
    float4 v = *(const float4*)(src + (size_t)base * 4);
    uint2 hp; hp.x = cvtpk(v.x, v.y); hp.y = cvtpk(v.z, v.w);
    *(uint2*)(dst + (size_t)base * 4) = hp;
}

// ------- QKV GEMM: 128x64 tile, BK=64, global_load_lds + XOR swizzle -------
// (r23 serial-staging version; 24KB LDS.) vtT written t-pre-permuted.
__global__ __launch_bounds__(256, 3) void gemm_qkv(
    const short* __restrict__ Ap,
    const short* __restrict__ Wq, const short* __restrict__ Wk, const short* __restrict__ Wv,
    short* __restrict__ qh, short* __restrict__ kh, short* __restrict__ vtT,
    float* __restrict__ qnsT, float2* __restrict__ knpk,
    const float* __restrict__ p_logc)
{
    const int z = blockIdx.z;
    const short* Bp = (z == 0) ? Wq : (z == 1 ? Wk : Wv);
    const int K = 1024;

    __shared__ short As[128 * 64];
    __shared__ short Bs[64 * 64];

    const int tid = threadIdx.x;
    const int wv = tid >> 6, lane = tid & 63, quad = lane >> 4, l15 = lane & 15;
    const int bm = blockIdx.y * 128, bn = blockIdx.x * 64;

    const int lr8 = lane >> 3, lc8 = lane & 7;
    const int swz8 = (lc8 ^ lr8) * 8;          // source granule offset (shorts)

    const short* gAl = Ap + (size_t)(bm + lr8) * K + swz8;
    const short* gBl = Bp + (size_t)(bn + lr8) * K + swz8;

    f32x4 acc[2][4];
#pragma unroll
    for (int mt = 0; mt < 2; mt++)
#pragma unroll
        for (int j = 0; j < 4; j++) acc[mt][j] = (f32x4){0.f, 0.f, 0.f, 0.f};

    for (int k0 = 0; k0 < K; k0 += 64) {
        __syncthreads();
#pragma unroll
        for (int i = 0; i < 4; i++)
            gload_lds16(gAl + (size_t)((wv * 4 + i) * 8) * K + k0, &As[(wv * 4 + i) * 512]);
#pragma unroll
        for (int j = 0; j < 2; j++)
            gload_lds16(gBl + (size_t)((wv * 2 + j) * 8) * K + k0, &Bs[(wv * 2 + j) * 512]);
        __syncthreads();
#pragma unroll
        for (int w = 0; w < 2; w++) {
            const int xs = ((w * 4 + quad) ^ (l15 & 7)) * 8;
            bf16x8 fa0 = *(const bf16x8*)&As[(wv * 32 + l15) * 64 + xs];
            bf16x8 fa1 = *(const bf16x8*)&As[(wv * 32 + 16 + l15) * 64 + xs];
#pragma unroll
            for (int nt = 0; nt < 4; nt++) {
                bf16x8 fb = *(const bf16x8*)&Bs[(nt * 16 + l15) * 64 + xs];
                acc[0][nt] = __builtin_amdgcn_mfma_f32_16x16x32_bf16(fa0, fb, acc[0][nt], 0, 0, 0);
                acc[1][nt] = __builtin_amdgcn_mfma_f32_16x16x32_bf16(fa1, fb, acc[1][nt], 0, 0, 0);
            }
        }
    }

    const float c = softplusf_(p_logc[0]);
    const float sc = sqrtf(c);
    const float twoC = 2.f * c;
    const int h0 = blockIdx.x;

    if (z < 2) {
        short* yout = (z == 0) ? qh : kh;
#pragma unroll
        for (int mt = 0; mt < 2; mt++) {
            const int mbase = bm + wv * 32 + mt * 16;
            float fr[4];
#pragma unroll
            for (int r = 0; r < 4; r++) {
                float s2 = 0.f;
#pragma unroll
                for (int nt = 0; nt < 4; nt++) s2 += acc[mt][nt][r] * acc[mt][nt][r];
#pragma unroll
                for (int mk = 1; mk < 16; mk <<= 1) s2 += __shfl_xor(s2, mk, 64);
                float n = fmaxf(sqrtf(s2), EPS_);
                float fac = tanhf(sc * n) / (sc * n);
                fr[r] = fac;
                if (l15 == 0) {
                    int m = mbase + quad * 4 + r;
                    int bI = m >> 10, s = m & 1023;
                    float yns = s2 * fac * fac;
                    if (z == 0) {
                        qnsT[(size_t)(bI * Hh + h0) * Ss + s] = yns;
                    } else {
                        knpk[(size_t)(bI * Hh + h0) * Ss + s]
                            = make_float2(yns, twoC / (1.f - c * yns));
                    }
                }
            }
#pragma unroll
            for (int nt = 0; nt < 4; nt++)
#pragma unroll
                for (int r = 0; r < 4; r++) {
                    int m = mbase + quad * 4 + r;
                    yout[(size_t)m * Dd + bn + nt * 16 + l15] = f2bf(acc[mt][nt][r] * fr[r]);
                }
        }
    } else {
#pragma unroll
        for (int mt = 0; mt < 2; mt++) {
            const int mbase = bm + wv * 32 + mt * 16;
            float tr[4];
#pragma unroll
            for (int r = 0; r < 4; r++) {
                float s2 = 0.f;
#pragma unroll
                for (int nt = 0; nt < 4; nt++) s2 += acc[mt][nt][r] * acc[mt][nt][r];
#pragma unroll
                for (int mk = 1; mk < 16; mk <<= 1) s2 += __shfl_xor(s2, mk, 64);
                float n = fmaxf(sqrtf(s2), EPS_);
                float fac = tanhf(sc * n) / (sc * n);
                float yn = n * fac;
                float ycl = fminf(yn, 1.f / sc - EPS_);
                float f2 = atanhf(sc * ycl) / (sc * fmaxf(yn, EPS_));
                tr[r] = fac * f2;
            }
            const int m0 = mbase + quad * 4;
            const int bI = m0 >> 10, s0 = m0 & 1023;
            const int w6 = s0 & 63;
            const int s0p = (s0 & ~63)
                          | ((w6 >> 5) * 32 + ((w6 & 15) >> 2) * 8 + ((w6 >> 4) & 1) * 4);
#pragma unroll
            for (int nt = 0; nt < 4; nt++) {
                int d = nt * 16 + l15;
                uint2 pk;
                pk.x = cvtpk(acc[mt][nt][0] * tr[0], acc[mt][nt][1] * tr[1]);
                pk.y = cvtpk(acc[mt][nt][2] * tr[2], acc[mt][nt][3] * tr[3]);
                *(uint2*)&vtT[((size_t)(bI * Hh + h0) * DHh + d) * Ss + s0p] = pk;
            }
        }
    }
}

// ---- 4-wave flash attention, full-t per block, rotated pipeline ----
// Grid (bh=32, qt=16): XCD = bh%8. 64 q rows x 1024 t (16 chunks).
// Per chunk: ds_read K,V -> QK MFMA -> barrier(4 waves) -> stage(ch+2)
// + norms(ch+1) -> scores -> PV. Depth-2 staging; all waits >=1 chunk old.
// No split-K: in-register epilogue, no LDS exchange.
__global__ __launch_bounds__(256, 4) void attn_mfma(
    const short* __restrict__ qh, const short* __restrict__ kh, const short* __restrict__ vtT,
    const float* __restrict__ qnsT, const float2* __restrict__ knpk,
    short* __restrict__ ccb,
    const float* __restrict__ p_logc, const float* __restrict__ p_beta)
{
    const float c = softplusf_(p_logc[0]);
    const float sc = sqrtf(c);
    const float bp = softplusf_(p_beta[0]);
    const float nkc = -bp / sc;          // p = u^(-bp/sc) = 2^(nkc * log2 u)
    const float cap = 2.f * c * 1e5f;    // = 2c / EPS-clamped denom
    const float onePlus = 1.f + EPS_;

    const int bh = blockIdx.x, qt = blockIdx.y;
    const int b = bh >> 4, h = bh & 15;
    const int tid = threadIdx.x;
    const int wv = tid >> 6, lane = tid & 63;
    const int quad = lane >> 4, l15 = lane & 15;
    const int q = qt * 64 + wv * 16 + l15;

    __shared__ short Ks[2][4096];   // [buf][t x d, granule-swizzled]  16KB
    __shared__ short Vt[2][4096];   // [buf][d x permuted-t]           16KB

    const short* qb = qh + (size_t)(b * Ss + q) * Dd + h * DHh + quad * 8;
    bf16x8 qf0 = *(const bf16x8*)qb;
    bf16x8 qf1 = *(const bf16x8*)(qb + 32);

    const float qn = qnsT[(size_t)bh * Ss + q];
    const float irq = 1.f / (1.f - c * qn);

    f32x4 O4[4];
#pragma unroll
    for (int nt = 0; nt < 4; nt++) O4[nt] = (f32x4){0.f, 0.f, 0.f, 0.f};
    float lac = 0.f;

    const int lr8 = lane >> 3, lc8 = lane & 7;
    const float2* nb = knpk + (size_t)bh * Ss;
    // staging source bases (granule pre-swizzled: col granule = lc8 ^ lr8)
    const short* ksb = kh + (size_t)b * Ss * Dd + h * DHh + (lc8 ^ lr8) * 8;
    const short* vsb = vtT + (size_t)bh * DHh * Ss + (lc8 ^ lr8) * 8;

    // norm register A/B sets (even/odd chunks); static indexing via full unroll
    f32x4 nA0[4], nA1[4], nB0[4], nB1[4];

    // prologue: stage ch0->buf0, ch1->buf1 (depth 2); norms(ch0)->A
#pragma unroll
    for (int j = 0; j < 2; j++) {
        const int R = wv * 16 + j * 8;
        gload_lds16(ksb + (size_t)(R + lr8) * Dd, &Ks[0][R * 64]);
        gload_lds16(vsb + (size_t)(R + lr8) * Ss, &Vt[0][R * 64]);
        gload_lds16(ksb + (size_t)(64 + R + lr8) * Dd, &Ks[1][R * 64]);
        gload_lds16(vsb + (size_t)(R + lr8) * Ss + 64, &Vt[1][R * 64]);
    }
#pragma unroll
    for (int nt = 0; nt < 4; nt++) {
        const float2* np = nb + nt * 16 + quad * 4;
        nA0[nt] = *(const f32x4*)np;
        nA1[nt] = *(const f32x4*)(np + 2);
    }
    __syncthreads();

    const int xsl = (quad ^ (l15 & 7)) * 8;   // phys granule for logical quad

#pragma unroll
    for (int ch = 0; ch < 16; ch++) {
        const int cur = ch & 1;

        // (1) LDS reads: K frags then V frags
        bf16x8 k0[4], k1[4], v0[4], v1[4];
#pragma unroll
        for (int nt = 0; nt < 4; nt++) {
            k0[nt] = *(const bf16x8*)&Ks[cur][(nt * 16 + l15) * 64 + xsl];
            k1[nt] = *(const bf16x8*)&Ks[cur][(nt * 16 + l15) * 64 + (xsl ^ 32)];
        }
#pragma unroll
        for (int nt = 0; nt < 4; nt++) {
            v0[nt] = *(const bf16x8*)&Vt[cur][(nt * 16 + l15) * 64 + xsl];
            v1[nt] = *(const bf16x8*)&Vt[cur][(nt * 16 + l15) * 64 + (xsl ^ 32)];
        }

        // (2) S^T = K * Q^T
        f32x4 acc[4];
        __builtin_amdgcn_s_setprio(1);
#pragma unroll
        for (int nt = 0; nt < 4; nt++) {
            f32x4 a = (f32x4){0.f, 0.f, 0.f, 0.f};
            a = __builtin_amdgcn_mfma_f32_16x16x32_bf16(k0[nt], qf0, a, 0, 0, 0);
            a = __builtin_amdgcn_mfma_f32_16x16x32_bf16(k1[nt], qf1, a, 0, 0, 0);
            acc[nt] = a;
        }
        __builtin_amdgcn_s_setprio(0);

        // (3) barrier: all reads of buf cur done; outstanding vmem >=1 chunk old
        if (ch < 15) __syncthreads();

        // (4) stage ch+2 into the buffer just freed (cur)
        if (ch + 2 < 16) {
#pragma unroll
            for (int j = 0; j < 2; j++) {
                const int R = wv * 16 + j * 8;
                gload_lds16(ksb + (size_t)((ch + 2) * 64 + R + lr8) * Dd,
                            &Ks[cur][R * 64]);
                gload_lds16(vsb + (size_t)(R + lr8) * Ss + (ch + 2) * 64,
                            &Vt[cur][R * 64]);
            }
        }
        // (5) norms for ch+1 into the other register set
        if (ch + 1 < 16) {
#pragma unroll
            for (int nt = 0; nt < 4; nt++) {
                const float2* np = nb + (ch + 1) * 64 + nt * 16 + quad * 4;
                if ((ch & 1) == 0) { nB0[nt] = *(const f32x4*)np; nB1[nt] = *(const f32x4*)(np + 2); }
                else               { nA0[nt] = *(const f32x4*)np; nA1[nt] = *(const f32x4*)(np + 2); }
            }
        }

        // (6) scores from this chunk's norm set (loaded >=1 chunk ago)
        float sv[4][4];
#pragma unroll
        for (int nt = 0; nt < 4; nt++) {
#pragma unroll
            for (int r = 0; r < 4; r++) {
                float kn, ik2c;
                if ((ch & 1) == 0) {
                    kn   = (r < 2) ? nA0[nt][(r & 1) * 2]     : nA1[nt][(r & 1) * 2];
                    ik2c = (r < 2) ? nA0[nt][(r & 1) * 2 + 1] : nA1[nt][(r & 1) * 2 + 1];
                } else {
                    kn   = (r < 2) ? nB0[nt][(r & 1) * 2]     : nB1[nt][(r & 1) * 2];
                    ik2c = (r < 2) ? nB0[nt][(r & 1) * 2 + 1] : nB1[nt][(r & 1) * 2 + 1];
                }
                float dns = (qn + kn) - 2.f * acc[nt][r];
                float co  = fminf(irq * ik2c, cap);
                float arg = fmaxf(fmaf(co, dns, 1.f), onePlus);
                float u   = arg + FSQRT(fmaf(arg, arg, -1.f));
                float p   = FEXP2(nkc * FLOG2(u));
                sv[nt][r] = p;
                lac += p;
            }
        }

        union { unsigned u[4]; bf16x8 v; } p0, p1;
        p0.u[0] = cvtpk(sv[0][0], sv[0][1]); p0.u[1] = cvtpk(sv[0][2], sv[0][3]);
        p0.u[2] = cvtpk(sv[1][0], sv[1][1]); p0.u[3] = cvtpk(sv[1][2], sv[1][3]);
        p1.u[0] = cvtpk(sv[2][0], sv[2][1]); p1.u[1] = cvtpk(sv[2][2], sv[2][3]);
        p1.u[2] = cvtpk(sv[3][0], sv[3][1]); p1.u[3] = cvtpk(sv[3][2], sv[3][3]);

        // (7) O^T += V^T * P^T
        __builtin_amdgcn_s_setprio(1);
#pragma unroll
        for (int nt = 0; nt < 4; nt++) {
            O4[nt] = __builtin_amdgcn_mfma_f32_16x16x32_bf16(v0[nt], p0.v, O4[nt], 0, 0, 0);
            O4[nt] = __builtin_amdgcn_mfma_f32_16x16x32_bf16(v1[nt], p1.v, O4[nt], 0, 0, 0);
        }
        __builtin_amdgcn_s_setprio(0);
    }

    // row sum over quads (each quad covered a t-subset)
    lac += __shfl_xor(lac, 16, 64);
    lac += __shfl_xor(lac, 32, 64);
    const float il = 1.f / lac;

    // in-register epilogue (no split-K exchange)
    float ot[4][4], t2 = 0.f;
#pragma unroll
    for (int nt = 0; nt < 4; nt++)
#pragma unroll
        for (int r = 0; r < 4; r++) {
            float v = O4[nt][r] * il;
            ot[nt][r] = v;
            t2 += v * v;
        }
    t2 += __shfl_xor(t2, 16, 64);
    t2 += __shfl_xor(t2, 32, 64);        // sum over d = 64 (quad x nt x r)

    float n = fmaxf(sqrtf(t2), EPS_);
    float fac = tanhf(sc * n) / (sc * n);          // exp_map
    float y2 = t2 * fac * fac;
    float yn = fmaxf(sqrtf(y2), EPS_);
    float ycl = fminf(yn, 1.f / sc - EPS_);
    float fac2 = atanhf(sc * ycl) / (sc * yn);     // log_map
    float tot = fac * fac2;

    short* ob = ccb + (size_t)(b * Ss + q) * Dd + h * DHh;
#pragma unroll
    for (int nt = 0; nt < 4; nt++) {
        uint2 pk;
        pk.x = cvtpk(ot[nt][0] * tot, ot[nt][1] * tot);
        pk.y = cvtpk(ot[nt][2] * tot, ot[nt][3] * tot);
        *(uint2*)(ob + nt * 16 + quad * 4) = pk;
    }
}

// ------- output projection: 64x64 tile, BK=64, global_load_lds + swizzle -------
// (r23 serial-staging version; 16KB LDS.)
__global__ __launch_bounds__(256, 6) void gemm_out(
    const short* __restrict__ Ap, const short* __restrict__ Bp,
    float* __restrict__ Cp)
{
    const int K = 1024, N = 1024;
    __shared__ short As[64 * 64];
    __shared__ short Bs[64 * 64];
    const int tid = threadIdx.x;
    const int wv = tid >> 6, lane = tid & 63, quad = lane >> 4, l15 = lane & 15;
    const int bm = blockIdx.y * 64, bn = blockIdx.x * 64;

    const int lr8 = lane >> 3, lc8 = lane & 7;
    const int swz8 = (lc8 ^ lr8) * 8;

    const short* gAl = Ap + (size_t)(bm + lr8) * K + swz8;
    const short* gBl = Bp + (size_t)(bn + lr8) * K + swz8;

    f32x4 acc[4];
#pragma unroll
    for (int j = 0; j < 4; j++) acc[j] = (f32x4){0.f, 0.f, 0.f, 0.f};

    for (int k0 = 0; k0 < K; k0 += 64) {
        __syncthreads();
#pragma unroll
        for (int j = 0; j < 2; j++) {
            gload_lds16(gAl + (size_t)((wv * 2 + j) * 8) * K + k0, &As[(wv * 2 + j) * 512]);
            gload_lds16(gBl + (size_t)((wv * 2 + j) * 8) * K + k0, &Bs[(wv * 2 + j) * 512]);
        }
        __syncthreads();
#pragma unroll
        for (int w = 0; w < 2; w++) {
            const int xs = ((w * 4 + quad) ^ (l15 & 7)) * 8;
            bf16x8 fa = *(const bf16x8*)&As[(wv * 16 + l15) * 64 + xs];
#pragma unroll
            for (int nt = 0; nt < 4; nt++) {
                bf16x8 fb = *(const bf16x8*)&Bs[(nt * 16 + l15) * 64 + xs];
                acc[nt] = __builtin_amdgcn_mfma_f32_16x16x32_bf16(fa, fb, acc[nt], 0, 0, 0);
            }
        }
    }
#pragma unroll
    for (int nt = 0; nt < 4; nt++)
#pragma unroll
        for (int r = 0; r < 4; r++)
            Cp[(size_t)(bm + wv * 16 + quad * 4 + r) * N + bn + nt * 16 + l15] = acc[nt][r];
}

extern "C" void kernel_launch(void* const* d_in, const int* in_sizes, int n_in,
                              void* d_out, int out_size, void* d_ws, size_t ws_size,
                              hipStream_t stream)
{
    const float* x    = (const float*)d_in[0];
    const float* Wq   = (const float*)d_in[1];
    const float* Wk   = (const float*)d_in[2];
    const float* Wv   = (const float*)d_in[3];
    const float* Wo   = (const float*)d_in[4];
    const float* logc = (const float*)d_in[5];
    const float* beta = (const float*)d_in[6];
    float* out = (float*)d_out;

    const size_t M2 = 2097152, M1 = 1048576;
    short* ws    = (short*)d_ws;
    short* xh    = ws;                 // 2M shorts (dead after gemm_qkv; ccb aliases)
    short* wqh   = xh + M2;            // 1M each
    short* wkh   = wqh + M1;
    short* wvh   = wkh + M1;
    short* woh   = wvh + M1;
    short* qh    = woh + M1;           // 2M each
    short* kh    = qh + M2;
    short* vtT   = kh + M2;
    float* qnsT  = (float*)(vtT + M2); // 32K floats
    float2* knpk = (float2*)(qnsT + 32768);   // 32K float2
    short* ccb   = xh;                 // alias (xh dead after gemm_qkv)

    // 1) fp32 -> bf16
    split_all<<<dim3(6144), 256, 0, stream>>>(x, Wq, Wk, Wv, Wo, xh, wqh, wkh, wvh, woh);
    // 2) QKV projection + fused hyperbolic maps (async-staged 128x64 tiles)
    gemm_qkv<<<dim3(16, 16, 3), 256, 0, stream>>>(xh, wqh, wkh, wvh,
        qh, kh, vtT, qnsT, knpk, logc);
    // 3) 4-wave flash attention, full-t, rotated pipeline, XCD-pinned grid
    attn_mfma<<<dim3(32, 16, 1), 256, 0, stream>>>(qh, kh, vtT, qnsT, knpk,
        ccb, logc, beta);
    // 4) output projection (async-staged 64x64 tiles)
    gemm_out<<<dim3(16, 32), 256, 0, stream>>>(ccb, woh, out);
}

// Round 13
// 156.563 us; speedup vs baseline: 1.3448x; 1.3448x over previous
//
#include <hip/hip_runtime.h>
#include <math.h>

// HyperbolicMultiHeadAttention — round 26 (= r23 verbatim, the 155.39us best):
//  * r24 (dbuf GEMMs, 48KB) cost occupancy: +2.3us. r25 (de-grouped attn,
//    launch_bounds(256,4) + 16-chunk unroll) hit a VGPR cliff: 64 VGPR + 184MB
//    scratch writes, attn 96us. Both reverted.
//  * This is the proven config: serial-staged async GEMMs (qkv 128x64 @3/CU,
//    out 64x64 @6/CU), 8-wave attn with in-block split-K, rotated pipeline
//    (ds_read -> QK -> barrier -> stage(ch+2)+norms(ch+1) -> scores -> PV),
//    XCD-pinned grid (bh fastest).
// B=2, S=1024, D=1024, H=16, dh=64.

#define EPS_ 1e-5f

constexpr int Ss = 1024, Dd = 1024, Hh = 16, DHh = 64;

typedef __attribute__((ext_vector_type(8))) short bf16x8;
typedef __attribute__((ext_vector_type(4))) short s16x4;
typedef __attribute__((ext_vector_type(4))) float f32x4;

__device__ __forceinline__ float softplusf_(float x) {
    return (x > 20.f) ? x : log1pf(expf(x));
}
__device__ __forceinline__ short f2bf(float f) {
    union { float f; unsigned u; } v; v.f = f;
    unsigned r = v.u + 0x7FFFu + ((v.u >> 16) & 1u);   // RNE
    return (short)(r >> 16);
}
__device__ __forceinline__ unsigned pks(short a, short b) {
    return (unsigned)(unsigned short)a | ((unsigned)(unsigned short)b << 16);
}

#if __has_builtin(__builtin_amdgcn_cvt_pk_bf16_f32)
typedef __attribute__((ext_vector_type(2))) __bf16 bfp2;
__device__ __forceinline__ unsigned cvtpk(float a, float b) {
    union { bfp2 v; unsigned u; } x;
    x.v = __builtin_amdgcn_cvt_pk_bf16_f32(a, b);
    return x.u;
}
#else
__device__ __forceinline__ unsigned cvtpk(float a, float b) { return pks(f2bf(a), f2bf(b)); }
#endif

#if __has_builtin(__builtin_amdgcn_sqrtf)
#define FSQRT __builtin_amdgcn_sqrtf
#else
#define FSQRT sqrtf
#endif
#if __has_builtin(__builtin_amdgcn_logf)
#define FLOG2 __builtin_amdgcn_logf
#else
#define FLOG2 __log2f
#endif
#if __has_builtin(__builtin_amdgcn_exp2f)
#define FEXP2 __builtin_amdgcn_exp2f
#else
#define FEXP2 exp2f
#endif

// async global->LDS, 16B per lane, linear LDS dest (wave base + lane*16)
__device__ __forceinline__ void gload_lds16(const short* gp, short* lp) {
    __builtin_amdgcn_global_load_lds(
        (__attribute__((address_space(1))) void*)(void*)(const_cast<short*>(gp)),
        (__attribute__((address_space(3))) void*)(void*)(lp), 16, 0, 0);
}

// ---------------- fp32 -> bf16 conversion (x, Wq, Wk, Wv, Wo) ----------------
__global__ __launch_bounds__(256) void split_all(
    const float* __restrict__ x,  const float* __restrict__ Wq,
    const float* __restrict__ Wk, const float* __restrict__ Wv,
    const float* __restrict__ Wo,
    short* __restrict__ xh,  short* __restrict__ wqh,
    short* __restrict__ wkh, short* __restrict__ wvh, short* __restrict__ woh)
{
    int g = blockIdx.x * 256 + threadIdx.x;
    const float* src; short* dst; int base;
    if (g < 524288)       { src = x;  dst = xh;  base = g; }
    else if (g < 786432)  { src = Wq; dst = wqh; base = g - 524288; }
    else if (g < 1048576) { src = Wk; dst = wkh; base = g - 786432; }
    else if (g < 1310720) { src = Wv; dst = wvh; base = g - 1048576; }
    else                  { src = Wo; dst = woh; base = g - 1310720; }
    float4 v = *(const float4*)(src + (size_t)base * 4);
    uint2 hp; hp.x = cvtpk(v.x, v.y); hp.y = cvtpk(v.z, v.w);
    *(uint2*)(dst + (size_t)base * 4) = hp;
}

// ------- QKV GEMM: 128x64 tile, BK=64, global_load_lds + XOR swizzle -------
// vtT is written with t pre-permuted by slot(w)=(w>>5)*32+((w&15)>>2)*8+
// ((w>>4)&1)*4+(w&3) within each 64-block, so attn PV A-frags are plain
// granule loads.
__global__ __launch_bounds__(256, 3) void gemm_qkv(
    const short* __restrict__ Ap,
    const short* __restrict__ Wq, const short* __restrict__ Wk, const short* __restrict__ Wv,
    short* __restrict__ qh, short* __restrict__ kh, short* __restrict__ vtT,
    float* __restrict__ qnsT, float2* __restrict__ knpk,
    const float* __restrict__ p_logc)
{
    const int z = blockIdx.z;
    const short* Bp = (z == 0) ? Wq : (z == 1 ? Wk : Wv);
    const int K = 1024;

    __shared__ short As[128 * 64];
    __shared__ short Bs[64 * 64];

    const int tid = threadIdx.x;
    const int wv = tid >> 6, lane = tid & 63, quad = lane >> 4, l15 = lane & 15;
    const int bm = blockIdx.y * 128, bn = blockIdx.x * 64;

    const int lr8 = lane >> 3, lc8 = lane & 7;
    const int swz8 = (lc8 ^ lr8) * 8;          // source granule offset (shorts)

    const short* gAl = Ap + (size_t)(bm + lr8) * K + swz8;
    const short* gBl = Bp + (size_t)(bn + lr8) * K + swz8;

    f32x4 acc[2][4];
#pragma unroll
    for (int mt = 0; mt < 2; mt++)
#pragma unroll
        for (int j = 0; j < 4; j++) acc[mt][j] = (f32x4){0.f, 0.f, 0.f, 0.f};

    for (int k0 = 0; k0 < K; k0 += 64) {
        __syncthreads();
#pragma unroll
        for (int i = 0; i < 4; i++)
            gload_lds16(gAl + (size_t)((wv * 4 + i) * 8) * K + k0, &As[(wv * 4 + i) * 512]);
#pragma unroll
        for (int j = 0; j < 2; j++)
            gload_lds16(gBl + (size_t)((wv * 2 + j) * 8) * K + k0, &Bs[(wv * 2 + j) * 512]);
        __syncthreads();
#pragma unroll
        for (int w = 0; w < 2; w++) {
            const int xs = ((w * 4 + quad) ^ (l15 & 7)) * 8;
            bf16x8 fa0 = *(const bf16x8*)&As[(wv * 32 + l15) * 64 + xs];
            bf16x8 fa1 = *(const bf16x8*)&As[(wv * 32 + 16 + l15) * 64 + xs];
#pragma unroll
            for (int nt = 0; nt < 4; nt++) {
                bf16x8 fb = *(const bf16x8*)&Bs[(nt * 16 + l15) * 64 + xs];
                acc[0][nt] = __builtin_amdgcn_mfma_f32_16x16x32_bf16(fa0, fb, acc[0][nt], 0, 0, 0);
                acc[1][nt] = __builtin_amdgcn_mfma_f32_16x16x32_bf16(fa1, fb, acc[1][nt], 0, 0, 0);
            }
        }
    }

    const float c = softplusf_(p_logc[0]);
    const float sc = sqrtf(c);
    const float twoC = 2.f * c;
    const int h0 = blockIdx.x;

    if (z < 2) {
        short* yout = (z == 0) ? qh : kh;
#pragma unroll
        for (int mt = 0; mt < 2; mt++) {
            const int mbase = bm + wv * 32 + mt * 16;
            float fr[4];
#pragma unroll
            for (int r = 0; r < 4; r++) {
                float s2 = 0.f;
#pragma unroll
                for (int nt = 0; nt < 4; nt++) s2 += acc[mt][nt][r] * acc[mt][nt][r];
#pragma unroll
                for (int mk = 1; mk < 16; mk <<= 1) s2 += __shfl_xor(s2, mk, 64);
                float n = fmaxf(sqrtf(s2), EPS_);
                float fac = tanhf(sc * n) / (sc * n);
                fr[r] = fac;
                if (l15 == 0) {
                    int m = mbase + quad * 4 + r;
                    int bI = m >> 10, s = m & 1023;
                    float yns = s2 * fac * fac;
                    if (z == 0) {
                        qnsT[(size_t)(bI * Hh + h0) * Ss + s] = yns;
                    } else {
                        knpk[(size_t)(bI * Hh + h0) * Ss + s]
                            = make_float2(yns, twoC / (1.f - c * yns));
                    }
                }
            }
#pragma unroll
            for (int nt = 0; nt < 4; nt++)
#pragma unroll
                for (int r = 0; r < 4; r++) {
                    int m = mbase + quad * 4 + r;
                    yout[(size_t)m * Dd + bn + nt * 16 + l15] = f2bf(acc[mt][nt][r] * fr[r]);
                }
        }
    } else {
#pragma unroll
        for (int mt = 0; mt < 2; mt++) {
            const int mbase = bm + wv * 32 + mt * 16;
            float tr[4];
#pragma unroll
            for (int r = 0; r < 4; r++) {
                float s2 = 0.f;
#pragma unroll
                for (int nt = 0; nt < 4; nt++) s2 += acc[mt][nt][r] * acc[mt][nt][r];
#pragma unroll
                for (int mk = 1; mk < 16; mk <<= 1) s2 += __shfl_xor(s2, mk, 64);
                float n = fmaxf(sqrtf(s2), EPS_);
                float fac = tanhf(sc * n) / (sc * n);
                float yn = n * fac;
                float ycl = fminf(yn, 1.f / sc - EPS_);
                float f2 = atanhf(sc * ycl) / (sc * fmaxf(yn, EPS_));
                tr[r] = fac * f2;
            }
            const int m0 = mbase + quad * 4;
            const int bI = m0 >> 10, s0 = m0 & 1023;
            const int w6 = s0 & 63;
            const int s0p = (s0 & ~63)
                          | ((w6 >> 5) * 32 + ((w6 & 15) >> 2) * 8 + ((w6 >> 4) & 1) * 4);
#pragma unroll
            for (int nt = 0; nt < 4; nt++) {
                int d = nt * 16 + l15;
                uint2 pk;
                pk.x = cvtpk(acc[mt][nt][0] * tr[0], acc[mt][nt][1] * tr[1]);
                pk.y = cvtpk(acc[mt][nt][2] * tr[2], acc[mt][nt][3] * tr[3]);
                *(uint2*)&vtT[((size_t)(bI * Hh + h0) * DHh + d) * Ss + s0p] = pk;
            }
        }
    }
}

// ---- 8-wave flash attention: in-block split-K, rotated pipeline ----
// Grid (bh=32, qt=16): XCD = bh%8 -> per-(b,h) K/V pinned to one L2.
// Per chunk: ds_read K,V -> QK MFMA -> barrier -> stage(ch+2)+norms(ch+1)
// -> scores -> PV. Depth-2 staging; all waits retire >=1-chunk-old loads.
__global__ __launch_bounds__(512) void attn_mfma(
    const short* __restrict__ qh, const short* __restrict__ kh, const short* __restrict__ vtT,
    const float* __restrict__ qnsT, const float2* __restrict__ knpk,
    short* __restrict__ ccb,
    const float* __restrict__ p_logc, const float* __restrict__ p_beta)
{
    const float c = softplusf_(p_logc[0]);
    const float sc = sqrtf(c);
    const float bp = softplusf_(p_beta[0]);
    const float nkc = -bp / sc;          // p = u^(-bp/sc) = 2^(nkc * log2 u)
    const float cap = 2.f * c * 1e5f;    // = 2c / EPS-clamped denom
    const float onePlus = 1.f + EPS_;

    const int bh = blockIdx.x, qt = blockIdx.y;
    const int b = bh >> 4, h = bh & 15;
    const int tid = threadIdx.x;
    const int wv = tid >> 6, lane = tid & 63;
    const int g = wv >> 2, w4 = wv & 3;
    const int quad = lane >> 4, l15 = lane & 15;
    const int q = qt * 64 + w4 * 16 + l15;

    __shared__ short Ks[2][2][4096];   // [group][buf][t x d, granule-swizzled]
    __shared__ short Vt[2][2][4096];   // [group][buf][d x permuted-t]

    const short* qb = qh + (size_t)(b * Ss + q) * Dd + h * DHh + quad * 8;
    bf16x8 qf0 = *(const bf16x8*)qb;
    bf16x8 qf1 = *(const bf16x8*)(qb + 32);

    const float qn = qnsT[(size_t)bh * Ss + q];
    const float irq = 1.f / (1.f - c * qn);

    f32x4 O4[4];
#pragma unroll
    for (int nt = 0; nt < 4; nt++) O4[nt] = (f32x4){0.f, 0.f, 0.f, 0.f};
    float lac = 0.f;

    const int tbase = g * 512;
    const int lr8 = lane >> 3, lc8 = lane & 7;
    const float2* nb = knpk + (size_t)bh * Ss;
    // staging source bases (granule pre-swizzled: col granule = lc8 ^ lr8)
    const short* ksb = kh + (size_t)b * Ss * Dd + h * DHh + (lc8 ^ lr8) * 8;
    const short* vsb = vtT + (size_t)bh * DHh * Ss + tbase + (lc8 ^ lr8) * 8;

    // norm register A/B sets (even/odd chunks); static indexing via full unroll
    f32x4 nA0[4], nA1[4], nB0[4], nB1[4];

    // prologue: stage ch0->buf0, ch1->buf1 (depth 2); norms(ch0)->A
#pragma unroll
    for (int j = 0; j < 2; j++) {
        const int R = w4 * 16 + j * 8;
        gload_lds16(ksb + (size_t)(tbase + R + lr8) * Dd, &Ks[g][0][R * 64]);
        gload_lds16(vsb + (size_t)(R + lr8) * Ss, &Vt[g][0][R * 64]);
        gload_lds16(ksb + (size_t)(tbase + 64 + R + lr8) * Dd, &Ks[g][1][R * 64]);
        gload_lds16(vsb + (size_t)(R + lr8) * Ss + 64, &Vt[g][1][R * 64]);
    }
#pragma unroll
    for (int nt = 0; nt < 4; nt++) {
        const float2* np = nb + tbase + nt * 16 + quad * 4;
        nA0[nt] = *(const f32x4*)np;
        nA1[nt] = *(const f32x4*)(np + 2);
    }
    __syncthreads();

    const int xsl = (quad ^ (l15 & 7)) * 8;   // phys granule for logical quad

#pragma unroll
    for (int ch = 0; ch < 8; ch++) {
        const int cur = ch & 1;

        // (1) LDS reads: K frags then V frags
        bf16x8 k0[4], k1[4], v0[4], v1[4];
#pragma unroll
        for (int nt = 0; nt < 4; nt++) {
            k0[nt] = *(const bf16x8*)&Ks[g][cur][(nt * 16 + l15) * 64 + xsl];
            k1[nt] = *(const bf16x8*)&Ks[g][cur][(nt * 16 + l15) * 64 + (xsl ^ 32)];
        }
#pragma unroll
        for (int nt = 0; nt < 4; nt++) {
            v0[nt] = *(const bf16x8*)&Vt[g][cur][(nt * 16 + l15) * 64 + xsl];
            v1[nt] = *(const bf16x8*)&Vt[g][cur][(nt * 16 + l15) * 64 + (xsl ^ 32)];
        }

        // (2) S^T = K * Q^T
        f32x4 acc[4];
        __builtin_amdgcn_s_setprio(1);
#pragma unroll
        for (int nt = 0; nt < 4; nt++) {
            f32x4 a = (f32x4){0.f, 0.f, 0.f, 0.f};
            a = __builtin_amdgcn_mfma_f32_16x16x32_bf16(k0[nt], qf0, a, 0, 0, 0);
            a = __builtin_amdgcn_mfma_f32_16x16x32_bf16(k1[nt], qf1, a, 0, 0, 0);
            acc[nt] = a;
        }
        __builtin_amdgcn_s_setprio(0);

        // (3) barrier: all reads of buf cur done; outstanding vmem >=1 chunk old
        if (ch < 7) __syncthreads();

        // (4) stage ch+2 into the buffer just freed (cur)
        if (ch + 2 < 8) {
#pragma unroll
            for (int j = 0; j < 2; j++) {
                const int R = w4 * 16 + j * 8;
                gload_lds16(ksb + (size_t)(tbase + (ch + 2) * 64 + R + lr8) * Dd,
                            &Ks[g][cur][R * 64]);
                gload_lds16(vsb + (size_t)(R + lr8) * Ss + (ch + 2) * 64,
                            &Vt[g][cur][R * 64]);
            }
        }
        // (5) norms for ch+1 into the other register set
        if (ch + 1 < 8) {
#pragma unroll
            for (int nt = 0; nt < 4; nt++) {
                const float2* np = nb + tbase + (ch + 1) * 64 + nt * 16 + quad * 4;
                if ((ch & 1) == 0) { nB0[nt] = *(const f32x4*)np; nB1[nt] = *(const f32x4*)(np + 2); }
                else               { nA0[nt] = *(const f32x4*)np; nA1[nt] = *(const f32x4*)(np + 2); }
            }
        }

        // (6) scores from this chunk's norm set (loaded >=1 chunk ago)
        float sv[4][4];
#pragma unroll
        for (int nt = 0; nt < 4; nt++) {
#pragma unroll
            for (int r = 0; r < 4; r++) {
                float kn, ik2c;
                if ((ch & 1) == 0) {
                    kn   = (r < 2) ? nA0[nt][(r & 1) * 2]     : nA1[nt][(r & 1) * 2];
                    ik2c = (r < 2) ? nA0[nt][(r & 1) * 2 + 1] : nA1[nt][(r & 1) * 2 + 1];
                } else {
                    kn   = (r < 2) ? nB0[nt][(r & 1) * 2]     : nB1[nt][(r & 1) * 2];
                    ik2c = (r < 2) ? nB0[nt][(r & 1) * 2 + 1] : nB1[nt][(r & 1) * 2 + 1];
                }
                float dns = (qn + kn) - 2.f * acc[nt][r];
                float co  = fminf(irq * ik2c, cap);
                float arg = fmaxf(fmaf(co, dns, 1.f), onePlus);
                float u   = arg + FSQRT(fmaf(arg, arg, -1.f));
                float p   = FEXP2(nkc * FLOG2(u));
                sv[nt][r] = p;
                lac += p;
            }
        }

        union { unsigned u[4]; bf16x8 v; } p0, p1;
        p0.u[0] = cvtpk(sv[0][0], sv[0][1]); p0.u[1] = cvtpk(sv[0][2], sv[0][3]);
        p0.u[2] = cvtpk(sv[1][0], sv[1][1]); p0.u[3] = cvtpk(sv[1][2], sv[1][3]);
        p1.u[0] = cvtpk(sv[2][0], sv[2][1]); p1.u[1] = cvtpk(sv[2][2], sv[2][3]);
        p1.u[2] = cvtpk(sv[3][0], sv[3][1]); p1.u[3] = cvtpk(sv[3][2], sv[3][3]);

        // (7) O^T += V^T * P^T
        __builtin_amdgcn_s_setprio(1);
#pragma unroll
        for (int nt = 0; nt < 4; nt++) {
            O4[nt] = __builtin_amdgcn_mfma_f32_16x16x32_bf16(v0[nt], p0.v, O4[nt], 0, 0, 0);
            O4[nt] = __builtin_amdgcn_mfma_f32_16x16x32_bf16(v1[nt], p1.v, O4[nt], 0, 0, 0);
        }
        __builtin_amdgcn_s_setprio(0);
    }

    // per-q partial row-sum within group (reduce over quads)
    lac += __shfl_xor(lac, 16, 64);
    lac += __shfl_xor(lac, 32, 64);

    // ---- in-block split-K reduction (reuse dead K/V LDS) ----
    float* Ored = (float*)&Ks[0][0][0];    // 4096 floats = 16KB
    float* lred = (float*)&Vt[0][0][0];    // 64 floats
    __syncthreads();                       // all compute done before LDS reuse
    if (g == 1) {
#pragma unroll
        for (int nt = 0; nt < 4; nt++)
#pragma unroll
            for (int r = 0; r < 4; r++)
                Ored[((w4 * 4 + nt) * 16 + (quad * 4 + r)) * 16 + l15] = O4[nt][r];
        if (lane < 16) lred[w4 * 16 + lane] = lac;
    }
    __syncthreads();

    if (g == 0) {
        const float lt = lac + lred[w4 * 16 + l15];
        const float il = 1.f / lt;
        float ot[4][4], t2 = 0.f;
#pragma unroll
        for (int nt = 0; nt < 4; nt++)
#pragma unroll
            for (int r = 0; r < 4; r++) {
                float v = (O4[nt][r]
                    + Ored[((w4 * 4 + nt) * 16 + (quad * 4 + r)) * 16 + l15]) * il;
                ot[nt][r] = v;
                t2 += v * v;
            }
        t2 += __shfl_xor(t2, 16, 64);
        t2 += __shfl_xor(t2, 32, 64);        // sum over d = 64 (quad x nt x r)

        float n = fmaxf(sqrtf(t2), EPS_);
        float fac = tanhf(sc * n) / (sc * n);          // exp_map
        float y2 = t2 * fac * fac;
        float yn = fmaxf(sqrtf(y2), EPS_);
        float ycl = fminf(yn, 1.f / sc - EPS_);
        float fac2 = atanhf(sc * ycl) / (sc * yn);     // log_map
        float tot = fac * fac2;

        short* ob = ccb + (size_t)(b * Ss + q) * Dd + h * DHh;
#pragma unroll
        for (int nt = 0; nt < 4; nt++) {
            uint2 pk;
            pk.x = cvtpk(ot[nt][0] * tot, ot[nt][1] * tot);
            pk.y = cvtpk(ot[nt][2] * tot, ot[nt][3] * tot);
            *(uint2*)(ob + nt * 16 + quad * 4) = pk;
        }
    }
}

// ------- output projection: 64x64 tile, BK=64, global_load_lds + swizzle -------
__global__ __launch_bounds__(256, 6) void gemm_out(
    const short* __restrict__ Ap, const short* __restrict__ Bp,
    float* __restrict__ Cp)
{
    const int K = 1024, N = 1024;
    __shared__ short As[64 * 64];
    __shared__ short Bs[64 * 64];
    const int tid = threadIdx.x;
    const int wv = tid >> 6, lane = tid & 63, quad = lane >> 4, l15 = lane & 15;
    const int bm = blockIdx.y * 64, bn = blockIdx.x * 64;

    const int lr8 = lane >> 3, lc8 = lane & 7;
    const int swz8 = (lc8 ^ lr8) * 8;

    const short* gAl = Ap + (size_t)(bm + lr8) * K + swz8;
    const short* gBl = Bp + (size_t)(bn + lr8) * K + swz8;

    f32x4 acc[4];
#pragma unroll
    for (int j = 0; j < 4; j++) acc[j] = (f32x4){0.f, 0.f, 0.f, 0.f};

    for (int k0 = 0; k0 < K; k0 += 64) {
        __syncthreads();
#pragma unroll
        for (int j = 0; j < 2; j++) {
            gload_lds16(gAl + (size_t)((wv * 2 + j) * 8) * K + k0, &As[(wv * 2 + j) * 512]);
            gload_lds16(gBl + (size_t)((wv * 2 + j) * 8) * K + k0, &Bs[(wv * 2 + j) * 512]);
        }
        __syncthreads();
#pragma unroll
        for (int w = 0; w < 2; w++) {
            const int xs = ((w * 4 + quad) ^ (l15 & 7)) * 8;
            bf16x8 fa = *(const bf16x8*)&As[(wv * 16 + l15) * 64 + xs];
#pragma unroll
            for (int nt = 0; nt < 4; nt++) {
                bf16x8 fb = *(const bf16x8*)&Bs[(nt * 16 + l15) * 64 + xs];
                acc[nt] = __builtin_amdgcn_mfma_f32_16x16x32_bf16(fa, fb, acc[nt], 0, 0, 0);
            }
        }
    }
#pragma unroll
    for (int nt = 0; nt < 4; nt++)
#pragma unroll
        for (int r = 0; r < 4; r++)
            Cp[(size_t)(bm + wv * 16 + quad * 4 + r) * N + bn + nt * 16 + l15] = acc[nt][r];
}

extern "C" void kernel_launch(void* const* d_in, const int* in_sizes, int n_in,
                              void* d_out, int out_size, void* d_ws, size_t ws_size,
                              hipStream_t stream)
{
    const float* x    = (const float*)d_in[0];
    const float* Wq   = (const float*)d_in[1];
    const float* Wk   = (const float*)d_in[2];
    const float* Wv   = (const float*)d_in[3];
    const float* Wo   = (const float*)d_in[4];
    const float* logc = (const float*)d_in[5];
    const float* beta = (const float*)d_in[6];
    float* out = (float*)d_out;

    const size_t M2 = 2097152, M1 = 1048576;
    short* ws    = (short*)d_ws;
    short* xh    = ws;                 // 2M shorts (dead after gemm_qkv; ccb aliases)
    short* wqh   = xh + M2;            // 1M each
    short* wkh   = wqh + M1;
    short* wvh   = wkh + M1;
    short* woh   = wvh + M1;
    short* qh    = woh + M1;           // 2M each
    short* kh    = qh + M2;
    short* vtT   = kh + M2;
    float* qnsT  = (float*)(vtT + M2); // 32K floats
    float2* knpk = (float2*)(qnsT + 32768);   // 32K float2
    short* ccb   = xh;                 // alias (xh dead after gemm_qkv)

    // 1) fp32 -> bf16
    split_all<<<dim3(6144), 256, 0, stream>>>(x, Wq, Wk, Wv, Wo, xh, wqh, wkh, wvh, woh);
    // 2) QKV projection + fused hyperbolic maps (async-staged 128x64 tiles)
    gemm_qkv<<<dim3(16, 16, 3), 256, 0, stream>>>(xh, wqh, wkh, wvh,
        qh, kh, vtT, qnsT, knpk, logc);
    // 3) 8-wave flash attention, rotated pipeline, XCD-pinned grid
    attn_mfma<<<dim3(32, 16, 1), 512, 0, stream>>>(qh, kh, vtT, qnsT, knpk,
        ccb, logc, beta);
    // 4) output projection (async-staged 64x64 tiles)
    gemm_out<<<dim3(16, 32), 256, 0, stream>>>(ccb, woh, out);
}

// Round 14
// 153.375 us; speedup vs baseline: 1.3727x; 1.0208x over previous
//
#include <hip/hip_runtime.h>
#include <math.h>

// HyperbolicMultiHeadAttention — round 27 (r25 attn, spill-fixed):
//  * attn_mfma: de-grouped 4-wave/full-t structure (no split-K reduction,
//    4-wave barriers, 32KB LDS -> 4 blocks/CU) — r25's version of this hit a
//    VGPR cliff (launch_bounds(256,4) cap=128 + full 16-chunk unroll ->
//    184MB scratch writes). Fixed: plain launch_bounds(256) (no VGPR cap)
//    and #pragma unroll 2 (ch&1 still static per copy; live state bounded).
//  * gemm_qkv / gemm_out / split_all: r23/r26 verbatim.
// B=2, S=1024, D=1024, H=16, dh=64.

#define EPS_ 1e-5f

constexpr int Ss = 1024, Dd = 1024, Hh = 16, DHh = 64;

typedef __attribute__((ext_vector_type(8))) short bf16x8;
typedef __attribute__((ext_vector_type(4))) short s16x4;
typedef __attribute__((ext_vector_type(4))) float f32x4;

__device__ __forceinline__ float softplusf_(float x) {
    return (x > 20.f) ? x : log1pf(expf(x));
}
__device__ __forceinline__ short f2bf(float f) {
    union { float f; unsigned u; } v; v.f = f;
    unsigned r = v.u + 0x7FFFu + ((v.u >> 16) & 1u);   // RNE
    return (short)(r >> 16);
}
__device__ __forceinline__ unsigned pks(short a, short b) {
    return (unsigned)(unsigned short)a | ((unsigned)(unsigned short)b << 16);
}

#if __has_builtin(__builtin_amdgcn_cvt_pk_bf16_f32)
typedef __attribute__((ext_vector_type(2))) __bf16 bfp2;
__device__ __forceinline__ unsigned cvtpk(float a, float b) {
    union { bfp2 v; unsigned u; } x;
    x.v = __builtin_amdgcn_cvt_pk_bf16_f32(a, b);
    return x.u;
}
#else
__device__ __forceinline__ unsigned cvtpk(float a, float b) { return pks(f2bf(a), f2bf(b)); }
#endif

#if __has_builtin(__builtin_amdgcn_sqrtf)
#define FSQRT __builtin_amdgcn_sqrtf
#else
#define FSQRT sqrtf
#endif
#if __has_builtin(__builtin_amdgcn_logf)
#define FLOG2 __builtin_amdgcn_logf
#else
#define FLOG2 __log2f
#endif
#if __has_builtin(__builtin_amdgcn_exp2f)
#define FEXP2 __builtin_amdgcn_exp2f
#else
#define FEXP2 exp2f
#endif

// async global->LDS, 16B per lane, linear LDS dest (wave base + lane*16)
__device__ __forceinline__ void gload_lds16(const short* gp, short* lp) {
    __builtin_amdgcn_global_load_lds(
        (__attribute__((address_space(1))) void*)(void*)(const_cast<short*>(gp)),
        (__attribute__((address_space(3))) void*)(void*)(lp), 16, 0, 0);
}

// ---------------- fp32 -> bf16 conversion (x, Wq, Wk, Wv, Wo) ----------------
__global__ __launch_bounds__(256) void split_all(
    const float* __restrict__ x,  const float* __restrict__ Wq,
    const float* __restrict__ Wk, const float* __restrict__ Wv,
    const float* __restrict__ Wo,
    short* __restrict__ xh,  short* __restrict__ wqh,
    short* __restrict__ wkh, short* __restrict__ wvh, short* __restrict__ woh)
{
    int g = blockIdx.x * 256 + threadIdx.x;
    const float* src; short* dst; int base;
    if (g < 524288)       { src = x;  dst = xh;  base = g; }
    else if (g < 786432)  { src = Wq; dst = wqh; base = g - 524288; }
    else if (g < 1048576) { src = Wk; dst = wkh; base = g - 786432; }
    else if (g < 1310720) { src = Wv; dst = wvh; base = g - 1048576; }
    else                  { src = Wo; dst = woh; base = g - 1310720; }
    float4 v = *(const float4*)(src + (size_t)base * 4);
    uint2 hp; hp.x = cvtpk(v.x, v.y); hp.y = cvtpk(v.z, v.w);
    *(uint2*)(dst + (size_t)base * 4) = hp;
}

// ------- QKV GEMM: 128x64 tile, BK=64, global_load_lds + XOR swizzle -------
// vtT is written with t pre-permuted by slot(w)=(w>>5)*32+((w&15)>>2)*8+
// ((w>>4)&1)*4+(w&3) within each 64-block, so attn PV A-frags are plain
// granule loads.
__global__ __launch_bounds__(256, 3) void gemm_qkv(
    const short* __restrict__ Ap,
    const short* __restrict__ Wq, const short* __restrict__ Wk, const short* __restrict__ Wv,
    short* __restrict__ qh, short* __restrict__ kh, short* __restrict__ vtT,
    float* __restrict__ qnsT, float2* __restrict__ knpk,
    const float* __restrict__ p_logc)
{
    const int z = blockIdx.z;
    const short* Bp = (z == 0) ? Wq : (z == 1 ? Wk : Wv);
    const int K = 1024;

    __shared__ short As[128 * 64];
    __shared__ short Bs[64 * 64];

    const int tid = threadIdx.x;
    const int wv = tid >> 6, lane = tid & 63, quad = lane >> 4, l15 = lane & 15;
    const int bm = blockIdx.y * 128, bn = blockIdx.x * 64;

    const int lr8 = lane >> 3, lc8 = lane & 7;
    const int swz8 = (lc8 ^ lr8) * 8;          // source granule offset (shorts)

    const short* gAl = Ap + (size_t)(bm + lr8) * K + swz8;
    const short* gBl = Bp + (size_t)(bn + lr8) * K + swz8;

    f32x4 acc[2][4];
#pragma unroll
    for (int mt = 0; mt < 2; mt++)
#pragma unroll
        for (int j = 0; j < 4; j++) acc[mt][j] = (f32x4){0.f, 0.f, 0.f, 0.f};

    for (int k0 = 0; k0 < K; k0 += 64) {
        __syncthreads();
#pragma unroll
        for (int i = 0; i < 4; i++)
            gload_lds16(gAl + (size_t)((wv * 4 + i) * 8) * K + k0, &As[(wv * 4 + i) * 512]);
#pragma unroll
        for (int j = 0; j < 2; j++)
            gload_lds16(gBl + (size_t)((wv * 2 + j) * 8) * K + k0, &Bs[(wv * 2 + j) * 512]);
        __syncthreads();
#pragma unroll
        for (int w = 0; w < 2; w++) {
            const int xs = ((w * 4 + quad) ^ (l15 & 7)) * 8;
            bf16x8 fa0 = *(const bf16x8*)&As[(wv * 32 + l15) * 64 + xs];
            bf16x8 fa1 = *(const bf16x8*)&As[(wv * 32 + 16 + l15) * 64 + xs];
#pragma unroll
            for (int nt = 0; nt < 4; nt++) {
                bf16x8 fb = *(const bf16x8*)&Bs[(nt * 16 + l15) * 64 + xs];
                acc[0][nt] = __builtin_amdgcn_mfma_f32_16x16x32_bf16(fa0, fb, acc[0][nt], 0, 0, 0);
                acc[1][nt] = __builtin_amdgcn_mfma_f32_16x16x32_bf16(fa1, fb, acc[1][nt], 0, 0, 0);
            }
        }
    }

    const float c = softplusf_(p_logc[0]);
    const float sc = sqrtf(c);
    const float twoC = 2.f * c;
    const int h0 = blockIdx.x;

    if (z < 2) {
        short* yout = (z == 0) ? qh : kh;
#pragma unroll
        for (int mt = 0; mt < 2; mt++) {
            const int mbase = bm + wv * 32 + mt * 16;
            float fr[4];
#pragma unroll
            for (int r = 0; r < 4; r++) {
                float s2 = 0.f;
#pragma unroll
                for (int nt = 0; nt < 4; nt++) s2 += acc[mt][nt][r] * acc[mt][nt][r];
#pragma unroll
                for (int mk = 1; mk < 16; mk <<= 1) s2 += __shfl_xor(s2, mk, 64);
                float n = fmaxf(sqrtf(s2), EPS_);
                float fac = tanhf(sc * n) / (sc * n);
                fr[r] = fac;
                if (l15 == 0) {
                    int m = mbase + quad * 4 + r;
                    int bI = m >> 10, s = m & 1023;
                    float yns = s2 * fac * fac;
                    if (z == 0) {
                        qnsT[(size_t)(bI * Hh + h0) * Ss + s] = yns;
                    } else {
                        knpk[(size_t)(bI * Hh + h0) * Ss + s]
                            = make_float2(yns, twoC / (1.f - c * yns));
                    }
                }
            }
#pragma unroll
            for (int nt = 0; nt < 4; nt++)
#pragma unroll
                for (int r = 0; r < 4; r++) {
                    int m = mbase + quad * 4 + r;
                    yout[(size_t)m * Dd + bn + nt * 16 + l15] = f2bf(acc[mt][nt][r] * fr[r]);
                }
        }
    } else {
#pragma unroll
        for (int mt = 0; mt < 2; mt++) {
            const int mbase = bm + wv * 32 + mt * 16;
            float tr[4];
#pragma unroll
            for (int r = 0; r < 4; r++) {
                float s2 = 0.f;
#pragma unroll
                for (int nt = 0; nt < 4; nt++) s2 += acc[mt][nt][r] * acc[mt][nt][r];
#pragma unroll
                for (int mk = 1; mk < 16; mk <<= 1) s2 += __shfl_xor(s2, mk, 64);
                float n = fmaxf(sqrtf(s2), EPS_);
                float fac = tanhf(sc * n) / (sc * n);
                float yn = n * fac;
                float ycl = fminf(yn, 1.f / sc - EPS_);
                float f2 = atanhf(sc * ycl) / (sc * fmaxf(yn, EPS_));
                tr[r] = fac * f2;
            }
            const int m0 = mbase + quad * 4;
            const int bI = m0 >> 10, s0 = m0 & 1023;
            const int w6 = s0 & 63;
            const int s0p = (s0 & ~63)
                          | ((w6 >> 5) * 32 + ((w6 & 15) >> 2) * 8 + ((w6 >> 4) & 1) * 4);
#pragma unroll
            for (int nt = 0; nt < 4; nt++) {
                int d = nt * 16 + l15;
                uint2 pk;
                pk.x = cvtpk(acc[mt][nt][0] * tr[0], acc[mt][nt][1] * tr[1]);
                pk.y = cvtpk(acc[mt][nt][2] * tr[2], acc[mt][nt][3] * tr[3]);
                *(uint2*)&vtT[((size_t)(bI * Hh + h0) * DHh + d) * Ss + s0p] = pk;
            }
        }
    }
}

// ---- 4-wave flash attention, full-t per block, rotated pipeline ----
// Grid (bh=32, qt=16): XCD = bh%8. 64 q rows x 1024 t (16 chunks).
// Per chunk: ds_read K,V -> QK MFMA -> barrier(4 waves) -> stage(ch+2)
// + norms(ch+1) -> scores -> PV. Depth-2 staging. No split-K; in-register
// epilogue. unroll 2 keeps ch&1 static without r25's live-range explosion;
// no VGPR cap (r25's launch_bounds(256,4) caused 184MB scratch spill).
__global__ __launch_bounds__(256) void attn_mfma(
    const short* __restrict__ qh, const short* __restrict__ kh, const short* __restrict__ vtT,
    const float* __restrict__ qnsT, const float2* __restrict__ knpk,
    short* __restrict__ ccb,
    const float* __restrict__ p_logc, const float* __restrict__ p_beta)
{
    const float c = softplusf_(p_logc[0]);
    const float sc = sqrtf(c);
    const float bp = softplusf_(p_beta[0]);
    const float nkc = -bp / sc;          // p = u^(-bp/sc) = 2^(nkc * log2 u)
    const float cap = 2.f * c * 1e5f;    // = 2c / EPS-clamped denom
    const float onePlus = 1.f + EPS_;

    const int bh = blockIdx.x, qt = blockIdx.y;
    const int b = bh >> 4, h = bh & 15;
    const int tid = threadIdx.x;
    const int wv = tid >> 6, lane = tid & 63;
    const int quad = lane >> 4, l15 = lane & 15;
    const int q = qt * 64 + wv * 16 + l15;

    __shared__ short Ks[2][4096];   // [buf][t x d, granule-swizzled]  16KB
    __shared__ short Vt[2][4096];   // [buf][d x permuted-t]           16KB

    const short* qb = qh + (size_t)(b * Ss + q) * Dd + h * DHh + quad * 8;
    bf16x8 qf0 = *(const bf16x8*)qb;
    bf16x8 qf1 = *(const bf16x8*)(qb + 32);

    const float qn = qnsT[(size_t)bh * Ss + q];
    const float irq = 1.f / (1.f - c * qn);

    f32x4 O4[4];
#pragma unroll
    for (int nt = 0; nt < 4; nt++) O4[nt] = (f32x4){0.f, 0.f, 0.f, 0.f};
    float lac = 0.f;

    const int lr8 = lane >> 3, lc8 = lane & 7;
    const float2* nb = knpk + (size_t)bh * Ss;
    // staging source bases (granule pre-swizzled: col granule = lc8 ^ lr8)
    const short* ksb = kh + (size_t)b * Ss * Dd + h * DHh + (lc8 ^ lr8) * 8;
    const short* vsb = vtT + (size_t)bh * DHh * Ss + (lc8 ^ lr8) * 8;

    // norm register A/B sets (even/odd chunks); static per unroll-2 copy
    f32x4 nA0[4], nA1[4], nB0[4], nB1[4];

    // prologue: stage ch0->buf0, ch1->buf1 (depth 2); norms(ch0)->A
#pragma unroll
    for (int j = 0; j < 2; j++) {
        const int R = wv * 16 + j * 8;
        gload_lds16(ksb + (size_t)(R + lr8) * Dd, &Ks[0][R * 64]);
        gload_lds16(vsb + (size_t)(R + lr8) * Ss, &Vt[0][R * 64]);
        gload_lds16(ksb + (size_t)(64 + R + lr8) * Dd, &Ks[1][R * 64]);
        gload_lds16(vsb + (size_t)(R + lr8) * Ss + 64, &Vt[1][R * 64]);
    }
#pragma unroll
    for (int nt = 0; nt < 4; nt++) {
        const float2* np = nb + nt * 16 + quad * 4;
        nA0[nt] = *(const f32x4*)np;
        nA1[nt] = *(const f32x4*)(np + 2);
    }
    __syncthreads();

    const int xsl = (quad ^ (l15 & 7)) * 8;   // phys granule for logical quad

#pragma unroll 2
    for (int ch = 0; ch < 16; ch++) {
        const int cur = ch & 1;

        // (1) LDS reads: K frags then V frags
        bf16x8 k0[4], k1[4], v0[4], v1[4];
#pragma unroll
        for (int nt = 0; nt < 4; nt++) {
            k0[nt] = *(const bf16x8*)&Ks[cur][(nt * 16 + l15) * 64 + xsl];
            k1[nt] = *(const bf16x8*)&Ks[cur][(nt * 16 + l15) * 64 + (xsl ^ 32)];
        }
#pragma unroll
        for (int nt = 0; nt < 4; nt++) {
            v0[nt] = *(const bf16x8*)&Vt[cur][(nt * 16 + l15) * 64 + xsl];
            v1[nt] = *(const bf16x8*)&Vt[cur][(nt * 16 + l15) * 64 + (xsl ^ 32)];
        }

        // (2) S^T = K * Q^T
        f32x4 acc[4];
        __builtin_amdgcn_s_setprio(1);
#pragma unroll
        for (int nt = 0; nt < 4; nt++) {
            f32x4 a = (f32x4){0.f, 0.f, 0.f, 0.f};
            a = __builtin_amdgcn_mfma_f32_16x16x32_bf16(k0[nt], qf0, a, 0, 0, 0);
            a = __builtin_amdgcn_mfma_f32_16x16x32_bf16(k1[nt], qf1, a, 0, 0, 0);
            acc[nt] = a;
        }
        __builtin_amdgcn_s_setprio(0);

        // (3) barrier: all reads of buf cur done; outstanding vmem >=1 chunk old
        if (ch < 15) __syncthreads();

        // (4) stage ch+2 into the buffer just freed (cur)
        if (ch + 2 < 16) {
#pragma unroll
            for (int j = 0; j < 2; j++) {
                const int R = wv * 16 + j * 8;
                gload_lds16(ksb + (size_t)((ch + 2) * 64 + R + lr8) * Dd,
                            &Ks[cur][R * 64]);
                gload_lds16(vsb + (size_t)(R + lr8) * Ss + (ch + 2) * 64,
                            &Vt[cur][R * 64]);
            }
        }
        // (5) norms for ch+1 into the other register set
        if (ch + 1 < 16) {
#pragma unroll
            for (int nt = 0; nt < 4; nt++) {
                const float2* np = nb + (ch + 1) * 64 + nt * 16 + quad * 4;
                if ((ch & 1) == 0) { nB0[nt] = *(const f32x4*)np; nB1[nt] = *(const f32x4*)(np + 2); }
                else               { nA0[nt] = *(const f32x4*)np; nA1[nt] = *(const f32x4*)(np + 2); }
            }
        }

        // (6) scores from this chunk's norm set (loaded >=1 chunk ago)
        float sv[4][4];
#pragma unroll
        for (int nt = 0; nt < 4; nt++) {
#pragma unroll
            for (int r = 0; r < 4; r++) {
                float kn, ik2c;
                if ((ch & 1) == 0) {
                    kn   = (r < 2) ? nA0[nt][(r & 1) * 2]     : nA1[nt][(r & 1) * 2];
                    ik2c = (r < 2) ? nA0[nt][(r & 1) * 2 + 1] : nA1[nt][(r & 1) * 2 + 1];
                } else {
                    kn   = (r < 2) ? nB0[nt][(r & 1) * 2]     : nB1[nt][(r & 1) * 2];
                    ik2c = (r < 2) ? nB0[nt][(r & 1) * 2 + 1] : nB1[nt][(r & 1) * 2 + 1];
                }
                float dns = (qn + kn) - 2.f * acc[nt][r];
                float co  = fminf(irq * ik2c, cap);
                float arg = fmaxf(fmaf(co, dns, 1.f), onePlus);
                float u   = arg + FSQRT(fmaf(arg, arg, -1.f));
                float p   = FEXP2(nkc * FLOG2(u));
                sv[nt][r] = p;
                lac += p;
            }
        }

        union { unsigned u[4]; bf16x8 v; } p0, p1;
        p0.u[0] = cvtpk(sv[0][0], sv[0][1]); p0.u[1] = cvtpk(sv[0][2], sv[0][3]);
        p0.u[2] = cvtpk(sv[1][0], sv[1][1]); p0.u[3] = cvtpk(sv[1][2], sv[1][3]);
        p1.u[0] = cvtpk(sv[2][0], sv[2][1]); p1.u[1] = cvtpk(sv[2][2], sv[2][3]);
        p1.u[2] = cvtpk(sv[3][0], sv[3][1]); p1.u[3] = cvtpk(sv[3][2], sv[3][3]);

        // (7) O^T += V^T * P^T
        __builtin_amdgcn_s_setprio(1);
#pragma unroll
        for (int nt = 0; nt < 4; nt++) {
            O4[nt] = __builtin_amdgcn_mfma_f32_16x16x32_bf16(v0[nt], p0.v, O4[nt], 0, 0, 0);
            O4[nt] = __builtin_amdgcn_mfma_f32_16x16x32_bf16(v1[nt], p1.v, O4[nt], 0, 0, 0);
        }
        __builtin_amdgcn_s_setprio(0);
    }

    // row sum over quads (each quad covered a t-subset)
    lac += __shfl_xor(lac, 16, 64);
    lac += __shfl_xor(lac, 32, 64);
    const float il = 1.f / lac;

    // in-register epilogue (no split-K exchange)
    float ot[4][4], t2 = 0.f;
#pragma unroll
    for (int nt = 0; nt < 4; nt++)
#pragma unroll
        for (int r = 0; r < 4; r++) {
            float v = O4[nt][r] * il;
            ot[nt][r] = v;
            t2 += v * v;
        }
    t2 += __shfl_xor(t2, 16, 64);
    t2 += __shfl_xor(t2, 32, 64);        // sum over d = 64 (quad x nt x r)

    float n = fmaxf(sqrtf(t2), EPS_);
    float fac = tanhf(sc * n) / (sc * n);          // exp_map
    float y2 = t2 * fac * fac;
    float yn = fmaxf(sqrtf(y2), EPS_);
    float ycl = fminf(yn, 1.f / sc - EPS_);
    float fac2 = atanhf(sc * ycl) / (sc * yn);     // log_map
    float tot = fac * fac2;

    short* ob = ccb + (size_t)(b * Ss + q) * Dd + h * DHh;
#pragma unroll
    for (int nt = 0; nt < 4; nt++) {
        uint2 pk;
        pk.x = cvtpk(ot[nt][0] * tot, ot[nt][1] * tot);
        pk.y = cvtpk(ot[nt][2] * tot, ot[nt][3] * tot);
        *(uint2*)(ob + nt * 16 + quad * 4) = pk;
    }
}

// ------- output projection: 64x64 tile, BK=64, global_load_lds + swizzle -------
__global__ __launch_bounds__(256, 6) void gemm_out(
    const short* __restrict__ Ap, const short* __restrict__ Bp,
    float* __restrict__ Cp)
{
    const int K = 1024, N = 1024;
    __shared__ short As[64 * 64];
    __shared__ short Bs[64 * 64];
    const int tid = threadIdx.x;
    const int wv = tid >> 6, lane = tid & 63, quad = lane >> 4, l15 = lane & 15;
    const int bm = blockIdx.y * 64, bn = blockIdx.x * 64;

    const int lr8 = lane >> 3, lc8 = lane & 7;
    const int swz8 = (lc8 ^ lr8) * 8;

    const short* gAl = Ap + (size_t)(bm + lr8) * K + swz8;
    const short* gBl = Bp + (size_t)(bn + lr8) * K + swz8;

    f32x4 acc[4];
#pragma unroll
    for (int j = 0; j < 4; j++) acc[j] = (f32x4){0.f, 0.f, 0.f, 0.f};

    for (int k0 = 0; k0 < K; k0 += 64) {
        __syncthreads();
#pragma unroll
        for (int j = 0; j < 2; j++) {
            gload_lds16(gAl + (size_t)((wv * 2 + j) * 8) * K + k0, &As[(wv * 2 + j) * 512]);
            gload_lds16(gBl + (size_t)((wv * 2 + j) * 8) * K + k0, &Bs[(wv * 2 + j) * 512]);
        }
        __syncthreads();
#pragma unroll
        for (int w = 0; w < 2; w++) {
            const int xs = ((w * 4 + quad) ^ (l15 & 7)) * 8;
            bf16x8 fa = *(const bf16x8*)&As[(wv * 16 + l15) * 64 + xs];
#pragma unroll
            for (int nt = 0; nt < 4; nt++) {
                bf16x8 fb = *(const bf16x8*)&Bs[(nt * 16 + l15) * 64 + xs];
                acc[nt] = __builtin_amdgcn_mfma_f32_16x16x32_bf16(fa, fb, acc[nt], 0, 0, 0);
            }
        }
    }
#pragma unroll
    for (int nt = 0; nt < 4; nt++)
#pragma unroll
        for (int r = 0; r < 4; r++)
            Cp[(size_t)(bm + wv * 16 + quad * 4 + r) * N + bn + nt * 16 + l15] = acc[nt][r];
}

extern "C" void kernel_launch(void* const* d_in, const int* in_sizes, int n_in,
                              void* d_out, int out_size, void* d_ws, size_t ws_size,
                              hipStream_t stream)
{
    const float* x    = (const float*)d_in[0];
    const float* Wq   = (const float*)d_in[1];
    const float* Wk   = (const float*)d_in[2];
    const float* Wv   = (const float*)d_in[3];
    const float* Wo   = (const float*)d_in[4];
    const float* logc = (const float*)d_in[5];
    const float* beta = (const float*)d_in[6];
    float* out = (float*)d_out;

    const size_t M2 = 2097152, M1 = 1048576;
    short* ws    = (short*)d_ws;
    short* xh    = ws;                 // 2M shorts (dead after gemm_qkv; ccb aliases)
    short* wqh   = xh + M2;            // 1M each
    short* wkh   = wqh + M1;
    short* wvh   = wkh + M1;
    short* woh   = wvh + M1;
    short* qh    = woh + M1;           // 2M each
    short* kh    = qh + M2;
    short* vtT   = kh + M2;
    float* qnsT  = (float*)(vtT + M2); // 32K floats
    float2* knpk = (float2*)(qnsT + 32768);   // 32K float2
    short* ccb   = xh;                 // alias (xh dead after gemm_qkv)

    // 1) fp32 -> bf16
    split_all<<<dim3(6144), 256, 0, stream>>>(x, Wq, Wk, Wv, Wo, xh, wqh, wkh, wvh, woh);
    // 2) QKV projection + fused hyperbolic maps (async-staged 128x64 tiles)
    gemm_qkv<<<dim3(16, 16, 3), 256, 0, stream>>>(xh, wqh, wkh, wvh,
        qh, kh, vtT, qnsT, knpk, logc);
    // 3) 4-wave flash attention, full-t, rotated pipeline, XCD-pinned grid
    attn_mfma<<<dim3(32, 16, 1), 256, 0, stream>>>(qh, kh, vtT, qnsT, knpk,
        ccb, logc, beta);
    // 4) output projection (async-staged 64x64 tiles)
    gemm_out<<<dim3(16, 32), 256, 0, stream>>>(ccb, woh, out);
}